// Round 6
// baseline (383.790 us; speedup 1.0000x reference)
//
#include <hip/hip_runtime.h>
#include <hip/hip_bf16.h>
#include <math.h>

constexpr int B_   = 2;
constexpr int L_   = 1024;
constexpr int DM   = 1024;
constexpr int DI   = 2048;
constexpr int NS   = 16;
constexpr int DTR  = 64;
constexpr int TOK  = B_ * L_;
constexpr int NC   = 32;      // scan chunks; serial length 32; grid 2048 = 8 blocks/CU

typedef __attribute__((ext_vector_type(8))) short short8;
typedef __attribute__((ext_vector_type(4))) float f32x4;
using bf16 = __hip_bfloat16;

__device__ __forceinline__ float sigmoidf_(float v) {
    return 1.f / (1.f + __expf(-v));
}
__device__ __forceinline__ float softplusf_(float v) {
    return fmaxf(v, 0.f) + __logf(1.f + __expf(-fabsf(v)));
}

__device__ __forceinline__ f32x4 mfma16(short8 a, short8 b, f32x4 c) {
    return __builtin_amdgcn_mfma_f32_16x16x32_bf16(a, b, c, 0, 0, 0);
}

// ---------------- RMSNorm -> bf16 hi/lo split ----------------
__global__ __launch_bounds__(256) void k_rmsnorm(
    const float* __restrict__ x, const float* __restrict__ w,
    bf16* __restrict__ hh, bf16* __restrict__ hl)
{
    int row = blockIdx.x;
    const float4* xrp = (const float4*)(x + (size_t)row * DM);
    float4 v = xrp[threadIdx.x];
    float ss = v.x*v.x + v.y*v.y + v.z*v.z + v.w*v.w;
    #pragma unroll
    for (int m = 32; m >= 1; m >>= 1) ss += __shfl_xor(ss, m);
    __shared__ float acc[4];
    int wid = threadIdx.x >> 6, lane = threadIdx.x & 63;
    if (lane == 0) acc[wid] = ss;
    __syncthreads();
    float tot = acc[0] + acc[1] + acc[2] + acc[3];
    float sc = rsqrtf(tot * (1.f / DM) + 1e-5f);
    float4 wv = ((const float4*)w)[threadIdx.x];
    float o[4] = { v.x*sc*wv.x, v.y*sc*wv.y, v.z*sc*wv.z, v.w*sc*wv.w };
    alignas(8) bf16 H[4], Lo[4];
    #pragma unroll
    for (int j = 0; j < 4; ++j) {
        H[j]  = __float2bfloat16(o[j]);
        Lo[j] = __float2bfloat16(o[j] - __bfloat162float(H[j]));
    }
    size_t base = (size_t)row * DM + threadIdx.x * 4;
    *(ushort4*)(hh + base) = *(ushort4*)H;
    *(ushort4*)(hl + base) = *(ushort4*)Lo;
}

// ---------------- fp32 -> bf16 hi/lo split ----------------
__global__ __launch_bounds__(256) void k_split(
    const float* __restrict__ s, bf16* __restrict__ hi, bf16* __restrict__ lo, int n4)
{
    int i = blockIdx.x * 256 + threadIdx.x;
    if (i >= n4) return;
    float4 v = ((const float4*)s)[i];
    float f[4] = { v.x, v.y, v.z, v.w };
    alignas(8) bf16 H[4], Lo[4];
    #pragma unroll
    for (int j = 0; j < 4; ++j) {
        H[j]  = __float2bfloat16(f[j]);
        Lo[j] = __float2bfloat16(f[j] - __bfloat162float(H[j]));
    }
    *(ushort4*)(hi + (size_t)i * 4) = *(ushort4*)H;
    *(ushort4*)(lo + (size_t)i * 4) = *(ushort4*)Lo;
}

// split with row padding: src [96,2048] -> dst [128,2048] hi/lo, rows 96..127 = 0
__global__ __launch_bounds__(256) void k_split_pad(
    const float* __restrict__ s, bf16* __restrict__ hi, bf16* __restrict__ lo)
{
    int i = blockIdx.x * 256 + threadIdx.x;   // 65536 = 128*2048/4
    int row = i >> 9;
    float f[4] = {0.f, 0.f, 0.f, 0.f};
    if (row < 96) {
        float4 v = ((const float4*)s)[i];
        f[0] = v.x; f[1] = v.y; f[2] = v.z; f[3] = v.w;
    }
    alignas(8) bf16 H[4], Lo[4];
    #pragma unroll
    for (int j = 0; j < 4; ++j) {
        H[j]  = __float2bfloat16(f[j]);
        Lo[j] = __float2bfloat16(f[j] - __bfloat162float(H[j]));
    }
    *(ushort4*)(hi + (size_t)i * 4) = *(ushort4*)H;
    *(ushort4*)(lo + (size_t)i * 4) = *(ushort4*)Lo;
}

// ---------------- f32 transpose [TOK][DI] -> [DI][TOK] ----------------
__global__ __launch_bounds__(256) void k_transpose(
    const float* __restrict__ in, float* __restrict__ out)
{
    __shared__ float tile[32][33];
    int tx = threadIdx.x & 31, ty = threadIdx.x >> 5;   // ty 0..7
    int c0 = blockIdx.x * 32, r0 = blockIdx.y * 32;
    #pragma unroll
    for (int i = 0; i < 4; ++i)
        tile[ty * 4 + i][tx] = in[(size_t)(r0 + ty * 4 + i) * DI + c0 + tx];
    __syncthreads();
    #pragma unroll
    for (int i = 0; i < 4; ++i)
        out[(size_t)(c0 + ty * 4 + i) * TOK + r0 + tx] = tile[tx][ty * 4 + i];
}

// ---------------- B/C transpose: xdbl[tok][64+j] -> bc_t[j][tok], j<32 ----------------
__global__ __launch_bounds__(256) void k_tr_bc(
    const float* __restrict__ xdbl, float* __restrict__ bc_t)
{
    int id = blockIdx.x * 256 + threadIdx.x;   // 65536
    int tok = id & (TOK - 1);
    int j = id >> 11;
    bc_t[(size_t)j * TOK + tok] = xdbl[(size_t)tok * 96 + 64 + j];
}

// ---------------- bf16 split-GEMM via MFMA ----------------
// C[M,N] = A[M,K] * B[N,K]^T; A has NA parts, B has 2.
// EPI: 0 plain, 1 bias+softplus, 2 +resid, 3 atomicAdd col<Nb,
//      4 bias+softplus + TRANSPOSED float4 store (C is [N][ldc], ldc=row count)
__device__ __forceinline__ void stage_tile(const bf16* src, int ld, bf16* lds, int lane)
{
    #pragma unroll
    for (int j = 0; j < 8; ++j) {
        int c = (j << 6) + lane;
        int r = c >> 2;
        int g = (c & 3) ^ ((r >> 1) & 3);
        __builtin_amdgcn_global_load_lds(
            (const __attribute__((address_space(1))) unsigned int*)(src + (size_t)r * ld + (g << 3)),
            (__attribute__((address_space(3))) unsigned int*)(lds + (j << 9)),
            16, 0, 0);
    }
}

template<int NA, int EPI>
__global__ __launch_bounds__(256) void k_gemm_bf16(
    const bf16* __restrict__ Ah, const bf16* __restrict__ Al, int lda,
    const bf16* __restrict__ Bh, const bf16* __restrict__ Bl, int ldb,
    float* __restrict__ C, int ldc,
    const float* __restrict__ aux,      // bias (EPI=1/4) or resid (EPI=2)
    int M, int Nb, int Kc)              // Kc = K count for this block (split-K)
{
    __shared__ alignas(1024) bf16 sA[2][NA][128 * 32];
    __shared__ alignas(1024) bf16 sB[2][2][128 * 32];

    int tid = threadIdx.x, lane = tid & 63, wv = tid >> 6;
    int bm0 = blockIdx.y * 128, bn0 = blockIdx.x * 128;
    int kbase = blockIdx.z * Kc;
    int nkt = Kc >> 5;

    const bf16* Abase_h = Ah + (size_t)bm0 * lda + kbase;
    const bf16* Abase_l = (NA == 2) ? (Al + (size_t)bm0 * lda + kbase) : nullptr;
    const bf16* Bbase_h = Bh + (size_t)bn0 * ldb + kbase;
    const bf16* Bbase_l = Bl + (size_t)bn0 * ldb + kbase;

    auto stage_all = [&](int buf, int kt) {
        int k0 = kt << 5;
        if constexpr (NA == 2) {
            if      (wv == 0) stage_tile(Abase_h + k0, lda, &sA[buf][0][0], lane);
            else if (wv == 1) stage_tile(Abase_l + k0, lda, &sA[buf][1][0], lane);
            else if (wv == 2) stage_tile(Bbase_h + k0, ldb, &sB[buf][0][0], lane);
            else              stage_tile(Bbase_l + k0, ldb, &sB[buf][1][0], lane);
        } else {
            if      (wv == 0) stage_tile(Abase_h + k0, lda, &sA[buf][0][0], lane);
            else if (wv == 1) stage_tile(Bbase_h + k0, ldb, &sB[buf][0][0], lane);
            else if (wv == 2) stage_tile(Bbase_l + k0, ldb, &sB[buf][1][0], lane);
        }
    };
    auto frag = [&](const bf16* t, int r, int g) -> short8 {
        int c = (r << 2) + (g ^ ((r >> 1) & 3));
        return *(const short8*)(t + (c << 3));
    };

    int wr = (wv >> 1) << 6;
    int wc = (wv & 1) << 6;
    int fr = lane & 15, g = lane >> 4;

    f32x4 acc[4][4] = {};

    stage_all(0, 0);
    __syncthreads();
    for (int kt = 0; kt < nkt; ++kt) {
        int cur = kt & 1;
        if (kt + 1 < nkt) stage_all(cur ^ 1, kt + 1);
        short8 a0[4], a1[4], b0[4], b1[4];
        #pragma unroll
        for (int m = 0; m < 4; ++m) {
            a0[m] = frag(&sA[cur][0][0], wr + m * 16 + fr, g);
            if constexpr (NA == 2) a1[m] = frag(&sA[cur][NA - 1][0], wr + m * 16 + fr, g);
        }
        #pragma unroll
        for (int n = 0; n < 4; ++n) {
            b0[n] = frag(&sB[cur][0][0], wc + n * 16 + fr, g);
            b1[n] = frag(&sB[cur][1][0], wc + n * 16 + fr, g);
        }
        #pragma unroll
        for (int m = 0; m < 4; ++m)
            #pragma unroll
            for (int n = 0; n < 4; ++n) {
                acc[m][n] = mfma16(a0[m], b0[n], acc[m][n]);
                acc[m][n] = mfma16(a0[m], b1[n], acc[m][n]);
                if constexpr (NA == 2) acc[m][n] = mfma16(a1[m], b0[n], acc[m][n]);
            }
        __syncthreads();
    }

    int rbase = bm0 + wr + (g << 2);
    int cb = bn0 + wc + fr;
    if constexpr (EPI == 4) {
        // bias + softplus, store transposed: C[col][row], float4 over i
        #pragma unroll
        for (int m = 0; m < 4; ++m)
            #pragma unroll
            for (int n = 0; n < 4; ++n) {
                int col = cb + n * 16;
                float b_ = aux[col];
                float vv[4];
                #pragma unroll
                for (int i = 0; i < 4; ++i)
                    vv[i] = softplusf_(acc[m][n][i] + b_);
                *(float4*)&C[(size_t)col * ldc + rbase + m * 16] = *(float4*)vv;
            }
    } else {
        #pragma unroll
        for (int m = 0; m < 4; ++m)
            #pragma unroll
            for (int i = 0; i < 4; ++i) {
                int row = rbase + m * 16 + i;
                #pragma unroll
                for (int n = 0; n < 4; ++n) {
                    int col = cb + n * 16;
                    float v = acc[m][n][i];
                    if constexpr (EPI == 3) {
                        if (col < Nb) atomicAdd(&C[(size_t)row * ldc + col], v);
                    } else {
                        if constexpr (EPI == 1) v = softplusf_(v + aux[col]);
                        if constexpr (EPI == 2) v += aux[(size_t)row * ldc + col];
                        C[(size_t)row * ldc + col] = v;
                    }
                }
            }
    }
}

// ---------------- causal depthwise conv1d (K=4) + bias + SiLU ----------------
__global__ __launch_bounds__(256) void k_conv_silu(
    const float* __restrict__ xr, const float* __restrict__ w,
    const float* __restrict__ bconv, float* __restrict__ u,
    bf16* __restrict__ uh, bf16* __restrict__ ul)
{
    int idx = blockIdx.x * 256 + threadIdx.x;
    int dq = idx & 511;
    int l  = (idx >> 9) & 1023;
    int bb = idx >> 19;
    int dd = dq * 4;

    float4 wrow[4];
    #pragma unroll
    for (int j = 0; j < 4; j++)
        wrow[j] = *(const float4*)&w[(dd + j) * 4];
    float4 bias4 = *(const float4*)&bconv[dd];

    float acc[4] = { bias4.x, bias4.y, bias4.z, bias4.w };
    #pragma unroll
    for (int k = 0; k < 4; k++) {
        int lp = l - 3 + k;
        if (lp >= 0) {
            const float4 xv = *(const float4*)
                &xr[((size_t)(bb * L_ + lp)) * (2 * DI) + dd];
            const float xs_[4] = { xv.x, xv.y, xv.z, xv.w };
            #pragma unroll
            for (int j = 0; j < 4; j++)
                acc[j] = fmaf(xs_[j], ((const float*)&wrow[j])[k], acc[j]);
        }
    }
    float out[4];
    alignas(8) bf16 H[4], Lo[4];
    #pragma unroll
    for (int j = 0; j < 4; j++) {
        out[j] = acc[j] * sigmoidf_(acc[j]);
        H[j]  = __float2bfloat16(out[j]);
        Lo[j] = __float2bfloat16(out[j] - __bfloat162float(H[j]));
    }
    size_t base = ((size_t)(bb * L_ + l)) * DI + dd;
    *(float4*)&u[base] = *(float4*)out;
    *(ushort4*)(uh + base) = *(ushort4*)H;
    *(ushort4*)(ul + base) = *(ushort4*)Lo;
}

// ---------------- chunked selective scan (transposed inputs) ----------------
// Thread = (channel d, state-quad q). 64 channels x 4 quads = 256 thr/block.
// Grid = B * NC * (DI/64) = 2048 blocks (8/CU). float4 loads cover 4 timesteps.
// Pass A: local scan -> P (prod dA = exp(A*sum_dl)), S (end state).
__global__ __launch_bounds__(256) void k_scan_part(
    const float* __restrict__ delta_t, const float* __restrict__ u_t,
    const float* __restrict__ bc_t,    const float* __restrict__ A_log,
    float* __restrict__ P, float* __restrict__ S)
{
    int bx = blockIdx.x;               // 2048
    int c = bx & (NC - 1);
    int rest = bx >> 5;
    int b = rest >> 5;
    int d0 = (rest & 31) << 6;
    int t = threadIdx.x;
    int dl_ = t >> 2, q = t & 3;
    int d = d0 + dl_;

    float A_dn[4];
    #pragma unroll
    for (int j = 0; j < 4; ++j)
        A_dn[j] = -__expf(A_log[d * NS + q * 4 + j]);

    float s[4] = {};
    float dsum = 0.f;                  // prod dA == exp(A_dn * sum(dl))
    int tokb = b * L_ + c * (L_ / NC);
    const float* dbase = delta_t + (size_t)d * TOK + tokb;
    const float* ubase = u_t + (size_t)d * TOK + tokb;
    const float* Bbase = bc_t + (size_t)(q * 4) * TOK + tokb;

    for (int g = 0; g < (L_ / NC) / 4; ++g) {
        float4 dl4 = *(const float4*)(dbase + g * 4);
        float4 uu4 = *(const float4*)(ubase + g * 4);
        float Bm_[4][4];
        #pragma unroll
        for (int j = 0; j < 4; ++j) {
            float4 bv = *(const float4*)(Bbase + (size_t)j * TOK + g * 4);
            Bm_[j][0] = bv.x; Bm_[j][1] = bv.y; Bm_[j][2] = bv.z; Bm_[j][3] = bv.w;
        }
        const float dls[4] = {dl4.x, dl4.y, dl4.z, dl4.w};
        const float uus[4] = {uu4.x, uu4.y, uu4.z, uu4.w};
        #pragma unroll
        for (int k = 0; k < 4; ++k) {
            float dlu = dls[k] * uus[k];
            dsum += dls[k];
            #pragma unroll
            for (int j = 0; j < 4; ++j) {
                float e = __expf(dls[k] * A_dn[j]);
                s[j] = fmaf(e, s[j], dlu * Bm_[j][k]);
            }
        }
    }
    float p[4];
    #pragma unroll
    for (int j = 0; j < 4; ++j)
        p[j] = __expf(A_dn[j] * dsum);
    size_t o = (((size_t)(b * NC + c) * DI) + d) * NS + q * 4;
    *(float4*)&P[o] = *(float4*)p;
    *(float4*)&S[o] = *(float4*)s;
}

// Pass B: sequential chunk combine; init written IN-PLACE into S.
__global__ __launch_bounds__(256) void k_scan_comb(
    const float* __restrict__ P, float* __restrict__ S)
{
    int idx = blockIdx.x * 256 + threadIdx.x;  // 65536
    int n = idx & 15;
    int d = (idx >> 4) & (DI - 1);
    int b = idx >> 15;
    float carry = 0.f;
    #pragma unroll
    for (int c = 0; c < NC; ++c) {
        size_t o = (((size_t)(b * NC + c) * DI) + d) * NS + n;
        float Pv = P[o], Sv = S[o];
        S[o] = carry;
        carry = fmaf(Pv, carry, Sv);
    }
}

// Pass C: re-scan with init; quad allreduce; each lane writes tok0+q.
__global__ __launch_bounds__(256) void k_scan_y(
    const float* __restrict__ delta_t, const float* __restrict__ u_t,
    const float* __restrict__ bc_t,    const float* __restrict__ xr,
    const float* __restrict__ A_log,   const float* __restrict__ Dp,
    const float* __restrict__ init, bf16* __restrict__ y)
{
    int bx = blockIdx.x;               // 2048
    int c = bx & (NC - 1);
    int rest = bx >> 5;
    int b = rest >> 5;
    int d0 = (rest & 31) << 6;
    int t = threadIdx.x;
    int dl_ = t >> 2, q = t & 3;
    int d = d0 + dl_;

    float A_dn[4];
    #pragma unroll
    for (int j = 0; j < 4; ++j)
        A_dn[j] = -__expf(A_log[d * NS + q * 4 + j]);
    float Dd = Dp[d];

    size_t o = (((size_t)(b * NC + c) * DI) + d) * NS + q * 4;
    float4 s4 = *(const float4*)&init[o];
    float s[4] = {s4.x, s4.y, s4.z, s4.w};

    int tokb = b * L_ + c * (L_ / NC);
    const float* dbase = delta_t + (size_t)d * TOK + tokb;
    const float* ubase = u_t + (size_t)d * TOK + tokb;
    const float* Bbase = bc_t + (size_t)(q * 4) * TOK + tokb;
    const float* Cbase = bc_t + (size_t)(16 + q * 4) * TOK + tokb;

    for (int g = 0; g < (L_ / NC) / 4; ++g) {
        int tok0 = tokb + g * 4;
        float4 dl4 = *(const float4*)(dbase + g * 4);
        float4 uu4 = *(const float4*)(ubase + g * 4);
        float Bm_[4][4], Cm_[4][4];
        #pragma unroll
        for (int j = 0; j < 4; ++j) {
            float4 bv = *(const float4*)(Bbase + (size_t)j * TOK + g * 4);
            float4 cv = *(const float4*)(Cbase + (size_t)j * TOK + g * 4);
            Bm_[j][0] = bv.x; Bm_[j][1] = bv.y; Bm_[j][2] = bv.z; Bm_[j][3] = bv.w;
            Cm_[j][0] = cv.x; Cm_[j][1] = cv.y; Cm_[j][2] = cv.z; Cm_[j][3] = cv.w;
        }
        const float dls[4] = {dl4.x, dl4.y, dl4.z, dl4.w};
        const float uus[4] = {uu4.x, uu4.y, uu4.z, uu4.w};
        float py[4];
        #pragma unroll
        for (int k = 0; k < 4; ++k) {
            float dlu = dls[k] * uus[k];
            float a_ = 0.f;
            #pragma unroll
            for (int j = 0; j < 4; ++j) {
                float e = __expf(dls[k] * A_dn[j]);
                s[j] = fmaf(e, s[j], dlu * Bm_[j][k]);
                a_ = fmaf(s[j], Cm_[j][k], a_);
            }
            py[k] = a_;
        }
        // quad allreduce (lanes q=0..3 of this channel)
        #pragma unroll
        for (int k = 0; k < 4; ++k) {
            py[k] += __shfl_xor(py[k], 1);
            py[k] += __shfl_xor(py[k], 2);
        }
        // lane q handles timestep tok0+q
        float py_q = py[0], uu_q = uus[0];
        py_q = (q == 1) ? py[1] : py_q;  uu_q = (q == 1) ? uus[1] : uu_q;
        py_q = (q == 2) ? py[2] : py_q;  uu_q = (q == 2) ? uus[2] : uu_q;
        py_q = (q == 3) ? py[3] : py_q;  uu_q = (q == 3) ? uus[3] : uu_q;
        int tok = tok0 + q;
        float rr = xr[(size_t)tok * (2 * DI) + DI + d];
        float yv = fmaf(uu_q, Dd, py_q) * (rr * sigmoidf_(rr));
        y[(size_t)tok * DI + d] = __float2bfloat16(yv);
    }
}

extern "C" void kernel_launch(void* const* d_in, const int* in_sizes, int n_in,
                              void* d_out, int out_size, void* d_ws, size_t ws_size,
                              hipStream_t stream)
{
    const float* x       = (const float*)d_in[0];
    const float* norm_w  = (const float*)d_in[1];
    const float* in_proj = (const float*)d_in[2];
    const float* conv_w  = (const float*)d_in[3];
    const float* conv_b  = (const float*)d_in[4];
    const float* x_proj  = (const float*)d_in[5];
    const float* dt_w    = (const float*)d_in[6];
    const float* dt_b    = (const float*)d_in[7];
    const float* A_log   = (const float*)d_in[8];
    const float* Dp      = (const float*)d_in[9];
    const float* out_w   = (const float*)d_in[10];
    float* out = (float*)d_out;

    // ---- workspace layout (lifetime-aliased, max ~83.5 MB) ----
    constexpr size_t MB = 1u << 20;
    constexpr size_t KB = 1u << 10;
    char* Wb = (char*)d_ws;
    float* xr      = (float*)(Wb + 0);                  // 32MB  in_proj..scan_y
    bf16*  h_h     = (bf16*) (Wb + 32 * MB);            // 4MB   rms..in_proj
    bf16*  h_l     = (bf16*) (Wb + 36 * MB);            // 4MB
    float* u       = (float*)(Wb + 32 * MB);            // 16MB  conv..transpose (over h)
    float* Pbuf    = (float*)(Wb + 32 * MB);            // 8MB   scan_part..comb (over dead u)
    bf16*  y_h     = (bf16*) (Wb + 32 * MB);            // 8MB   scan_y..out_proj (over dead P)
    float* Sbuf    = (float*)(Wb + 40 * MB);            // 8MB   scan_part..scan_y (init in-place)
    bf16*  u_h     = (bf16*) (Wb + 48 * MB);            // 8MB   conv..x_proj
    bf16*  u_l     = (bf16*) (Wb + 56 * MB);            // 8MB
    float* delta_t = (float*)(Wb + 48 * MB);            // 16MB  dt_proj..scan_y (over u_h/l)
    bf16*  wo_h    = (bf16*) (Wb + 48 * MB);            // 4MB   split_wo (after scan_y)..out_proj
    bf16*  wo_l    = (bf16*) (Wb + 52 * MB);            // 4MB   (over dead delta_t)
    bf16*  wi_h    = (bf16*) (Wb + 64 * MB);            // 8MB   split..in_proj
    bf16*  wi_l    = (bf16*) (Wb + 72 * MB);            // 8MB
    float* u_t     = (float*)(Wb + 64 * MB);            // 16MB  transpose..scan_y (over wi)
    float* xdbl    = (float*)(Wb + 80 * MB);            // 768KB x_proj..dt_proj/tr_bc
    bf16*  xp_h    = (bf16*) (Wb + 80 * MB + 768 * KB); // 512KB split_pad..x_proj
    bf16*  xp_l    = (bf16*) (Wb + 81 * MB + 256 * KB); // 512KB
    float* bc_t    = (float*)(Wb + 81 * MB + 768 * KB); // 256KB tr_bc..scan_y
    bf16*  xdbl_h  = (bf16*) (Wb + 82 * MB);            // 384KB split..dt_proj
    bf16*  xdbl_l  = (bf16*) (Wb + 82 * MB + 384 * KB); // 384KB
    bf16*  dtw_h   = (bf16*) (Wb + 82 * MB + 768 * KB); // 256KB
    bf16*  dtw_l   = (bf16*) (Wb + 83 * MB);            // 256KB

    // 1) RMSNorm -> h hi/lo
    k_rmsnorm<<<TOK, 256, 0, stream>>>(x, norm_w, h_h, h_l);
    // 2) split in_proj weights
    k_split<<<4096, 256, 0, stream>>>(in_proj, wi_h, wi_l, (2 * DI * DM) / 4);
    // 3) in_proj: [2048,1024] x [4096,1024]^T -> xr  (bf16x3)
    k_gemm_bf16<2, 0><<<dim3(32, 16, 1), 256, 0, stream>>>(
        h_h, h_l, DM, wi_h, wi_l, DM, xr, 2 * DI, nullptr, TOK, 2 * DI, DM);
    // 4) conv + SiLU -> u f32 [tok,d] + u hi/lo bf16
    k_conv_silu<<<4096, 256, 0, stream>>>(xr, conv_w, conv_b, u, u_h, u_l);
    // 5) pad-split x_proj weights
    k_split_pad<<<256, 256, 0, stream>>>(x_proj, xp_h, xp_l);
    // 6) x_proj: split-K=8, bf16x3, atomic f32 -> xdbl [2048,96]
    hipMemsetAsync(xdbl, 0, (size_t)TOK * 96 * sizeof(float), stream);
    k_gemm_bf16<2, 3><<<dim3(1, 16, 8), 256, 0, stream>>>(
        u_h, u_l, DI, xp_h, xp_l, DI, xdbl, 96, nullptr, TOK, 96, DI / 8);
    // 7) transpose u -> u_t [DI][TOK] (wi dead)
    k_transpose<<<dim3(DI / 32, TOK / 32), 256, 0, stream>>>(u, u_t);
    // 8) B/C transpose -> bc_t [32][TOK]
    k_tr_bc<<<256, 256, 0, stream>>>(xdbl, bc_t);
    // 9) split dt weights + xdbl
    k_split<<<128, 256, 0, stream>>>(dt_w, dtw_h, dtw_l, (DI * DTR) / 4);
    k_split<<<192, 256, 0, stream>>>(xdbl, xdbl_h, xdbl_l, (TOK * 96) / 4);
    // 10) dt_proj + softplus -> delta_t [DI][TOK] (transposed epilogue; u_h/l dead)
    k_gemm_bf16<2, 4><<<dim3(16, 16, 1), 256, 0, stream>>>(
        xdbl_h, xdbl_l, 96, dtw_h, dtw_l, DTR, delta_t, TOK, dt_b, TOK, DI, DTR);
    // 11) chunked scan (NC=32): partials -> combine -> y (u f32 dead; P/S over it)
    k_scan_part<<<B_ * NC * (DI / 64), 256, 0, stream>>>(
        delta_t, u_t, bc_t, A_log, Pbuf, Sbuf);
    k_scan_comb<<<256, 256, 0, stream>>>(Pbuf, Sbuf);
    k_scan_y<<<B_ * NC * (DI / 64), 256, 0, stream>>>(
        delta_t, u_t, bc_t, xr, A_log, Dp, Sbuf, y_h);
    // 12) split out_proj weights (delta_t dead)
    k_split<<<2048, 256, 0, stream>>>(out_w, wo_h, wo_l, (DM * DI) / 4);
    // 13) out_proj + residual (bf16x2)
    k_gemm_bf16<1, 2><<<dim3(8, 16, 1), 256, 0, stream>>>(
        y_h, nullptr, DI, wo_h, wo_l, DI, out, DM, x, TOK, DM, DI);
}

// Round 7
// 368.152 us; speedup vs baseline: 1.0425x; 1.0425x over previous
//
#include <hip/hip_runtime.h>
#include <hip/hip_bf16.h>
#include <math.h>

constexpr int B_   = 2;
constexpr int L_   = 1024;
constexpr int DM   = 1024;
constexpr int DI   = 2048;
constexpr int NS   = 16;
constexpr int DTR  = 64;
constexpr int TOK  = B_ * L_;
constexpr int NC   = 32;      // scan chunks; serial length 32

typedef __attribute__((ext_vector_type(8))) short short8;
typedef __attribute__((ext_vector_type(4))) float f32x4;
using bf16 = __hip_bfloat16;

__device__ __forceinline__ float sigmoidf_(float v) {
    return 1.f / (1.f + __expf(-v));
}
__device__ __forceinline__ float softplusf_(float v) {
    return fmaxf(v, 0.f) + __logf(1.f + __expf(-fabsf(v)));
}

__device__ __forceinline__ f32x4 mfma16(short8 a, short8 b, f32x4 c) {
    return __builtin_amdgcn_mfma_f32_16x16x32_bf16(a, b, c, 0, 0, 0);
}

// ---------------- RMSNorm -> bf16 hi/lo split ----------------
__global__ __launch_bounds__(256) void k_rmsnorm(
    const float* __restrict__ x, const float* __restrict__ w,
    bf16* __restrict__ hh, bf16* __restrict__ hl)
{
    int row = blockIdx.x;
    const float4* xrp = (const float4*)(x + (size_t)row * DM);
    float4 v = xrp[threadIdx.x];
    float ss = v.x*v.x + v.y*v.y + v.z*v.z + v.w*v.w;
    #pragma unroll
    for (int m = 32; m >= 1; m >>= 1) ss += __shfl_xor(ss, m);
    __shared__ float acc[4];
    int wid = threadIdx.x >> 6, lane = threadIdx.x & 63;
    if (lane == 0) acc[wid] = ss;
    __syncthreads();
    float tot = acc[0] + acc[1] + acc[2] + acc[3];
    float sc = rsqrtf(tot * (1.f / DM) + 1e-5f);
    float4 wv = ((const float4*)w)[threadIdx.x];
    float o[4] = { v.x*sc*wv.x, v.y*sc*wv.y, v.z*sc*wv.z, v.w*sc*wv.w };
    alignas(8) bf16 H[4], Lo[4];
    #pragma unroll
    for (int j = 0; j < 4; ++j) {
        H[j]  = __float2bfloat16(o[j]);
        Lo[j] = __float2bfloat16(o[j] - __bfloat162float(H[j]));
    }
    size_t base = (size_t)row * DM + threadIdx.x * 4;
    *(ushort4*)(hh + base) = *(ushort4*)H;
    *(ushort4*)(hl + base) = *(ushort4*)Lo;
}

// ---------------- fp32 -> bf16 hi/lo split ----------------
__global__ __launch_bounds__(256) void k_split(
    const float* __restrict__ s, bf16* __restrict__ hi, bf16* __restrict__ lo, int n4)
{
    int i = blockIdx.x * 256 + threadIdx.x;
    if (i >= n4) return;
    float4 v = ((const float4*)s)[i];
    float f[4] = { v.x, v.y, v.z, v.w };
    alignas(8) bf16 H[4], Lo[4];
    #pragma unroll
    for (int j = 0; j < 4; ++j) {
        H[j]  = __float2bfloat16(f[j]);
        Lo[j] = __float2bfloat16(f[j] - __bfloat162float(H[j]));
    }
    *(ushort4*)(hi + (size_t)i * 4) = *(ushort4*)H;
    *(ushort4*)(lo + (size_t)i * 4) = *(ushort4*)Lo;
}

// split with row padding: src [96,2048] -> dst [128,2048] hi/lo, rows 96..127 = 0
__global__ __launch_bounds__(256) void k_split_pad(
    const float* __restrict__ s, bf16* __restrict__ hi, bf16* __restrict__ lo)
{
    int i = blockIdx.x * 256 + threadIdx.x;   // 65536 = 128*2048/4
    int row = i >> 9;
    float f[4] = {0.f, 0.f, 0.f, 0.f};
    if (row < 96) {
        float4 v = ((const float4*)s)[i];
        f[0] = v.x; f[1] = v.y; f[2] = v.z; f[3] = v.w;
    }
    alignas(8) bf16 H[4], Lo[4];
    #pragma unroll
    for (int j = 0; j < 4; ++j) {
        H[j]  = __float2bfloat16(f[j]);
        Lo[j] = __float2bfloat16(f[j] - __bfloat162float(H[j]));
    }
    *(ushort4*)(hi + (size_t)i * 4) = *(ushort4*)H;
    *(ushort4*)(lo + (size_t)i * 4) = *(ushort4*)Lo;
}

// ---- xdbl post: hi/lo split + B/C transpose in one pass ----
// block = one token (128 threads, col<96 active)
__global__ __launch_bounds__(128) void k_xdbl_post(
    const float* __restrict__ xdbl, bf16* __restrict__ hi, bf16* __restrict__ lo,
    float* __restrict__ bc_t)
{
    int tok = blockIdx.x, col = threadIdx.x;
    if (col >= 96) return;
    float v = xdbl[(size_t)tok * 96 + col];
    bf16 H = __float2bfloat16(v);
    hi[(size_t)tok * 96 + col] = H;
    lo[(size_t)tok * 96 + col] = __float2bfloat16(v - __bfloat162float(H));
    if (col >= 64) bc_t[(size_t)(col - 64) * TOK + tok] = v;
}

// ---------------- bf16 split-GEMM via MFMA ----------------
// C[M,N] = A[M,K] * B[N,K]^T; A has NA parts, B has 2.
// EPI: 0 plain, 1 bias+softplus, 2 +resid, 3 atomicAdd col<Nb,
//      4 bias+softplus + TRANSPOSED float4 store (C is [N][ldc], ldc=row count)
__device__ __forceinline__ void stage_tile(const bf16* src, int ld, bf16* lds, int lane)
{
    #pragma unroll
    for (int j = 0; j < 8; ++j) {
        int c = (j << 6) + lane;
        int r = c >> 2;
        int g = (c & 3) ^ ((r >> 1) & 3);
        __builtin_amdgcn_global_load_lds(
            (const __attribute__((address_space(1))) unsigned int*)(src + (size_t)r * ld + (g << 3)),
            (__attribute__((address_space(3))) unsigned int*)(lds + (j << 9)),
            16, 0, 0);
    }
}

template<int NA, int EPI>
__global__ __launch_bounds__(256) void k_gemm_bf16(
    const bf16* __restrict__ Ah, const bf16* __restrict__ Al, int lda,
    const bf16* __restrict__ Bh, const bf16* __restrict__ Bl, int ldb,
    float* __restrict__ C, int ldc,
    const float* __restrict__ aux,      // bias (EPI=1/4) or resid (EPI=2)
    int M, int Nb, int Kc)              // Kc = K count for this block (split-K)
{
    __shared__ alignas(1024) bf16 sA[2][NA][128 * 32];
    __shared__ alignas(1024) bf16 sB[2][2][128 * 32];

    int tid = threadIdx.x, lane = tid & 63, wv = tid >> 6;
    int bm0 = blockIdx.y * 128, bn0 = blockIdx.x * 128;
    int kbase = blockIdx.z * Kc;
    int nkt = Kc >> 5;

    const bf16* Abase_h = Ah + (size_t)bm0 * lda + kbase;
    const bf16* Abase_l = (NA == 2) ? (Al + (size_t)bm0 * lda + kbase) : nullptr;
    const bf16* Bbase_h = Bh + (size_t)bn0 * ldb + kbase;
    const bf16* Bbase_l = Bl + (size_t)bn0 * ldb + kbase;

    auto stage_all = [&](int buf, int kt) {
        int k0 = kt << 5;
        if constexpr (NA == 2) {
            if      (wv == 0) stage_tile(Abase_h + k0, lda, &sA[buf][0][0], lane);
            else if (wv == 1) stage_tile(Abase_l + k0, lda, &sA[buf][1][0], lane);
            else if (wv == 2) stage_tile(Bbase_h + k0, ldb, &sB[buf][0][0], lane);
            else              stage_tile(Bbase_l + k0, ldb, &sB[buf][1][0], lane);
        } else {
            if      (wv == 0) stage_tile(Abase_h + k0, lda, &sA[buf][0][0], lane);
            else if (wv == 1) stage_tile(Bbase_h + k0, ldb, &sB[buf][0][0], lane);
            else if (wv == 2) stage_tile(Bbase_l + k0, ldb, &sB[buf][1][0], lane);
        }
    };
    auto frag = [&](const bf16* t, int r, int g) -> short8 {
        int c = (r << 2) + (g ^ ((r >> 1) & 3));
        return *(const short8*)(t + (c << 3));
    };

    int wr = (wv >> 1) << 6;
    int wc = (wv & 1) << 6;
    int fr = lane & 15, g = lane >> 4;

    f32x4 acc[4][4] = {};

    stage_all(0, 0);
    __syncthreads();
    for (int kt = 0; kt < nkt; ++kt) {
        int cur = kt & 1;
        if (kt + 1 < nkt) stage_all(cur ^ 1, kt + 1);
        short8 a0[4], a1[4], b0[4], b1[4];
        #pragma unroll
        for (int m = 0; m < 4; ++m) {
            a0[m] = frag(&sA[cur][0][0], wr + m * 16 + fr, g);
            if constexpr (NA == 2) a1[m] = frag(&sA[cur][NA - 1][0], wr + m * 16 + fr, g);
        }
        #pragma unroll
        for (int n = 0; n < 4; ++n) {
            b0[n] = frag(&sB[cur][0][0], wc + n * 16 + fr, g);
            b1[n] = frag(&sB[cur][1][0], wc + n * 16 + fr, g);
        }
        #pragma unroll
        for (int m = 0; m < 4; ++m)
            #pragma unroll
            for (int n = 0; n < 4; ++n) {
                acc[m][n] = mfma16(a0[m], b0[n], acc[m][n]);
                acc[m][n] = mfma16(a0[m], b1[n], acc[m][n]);
                if constexpr (NA == 2) acc[m][n] = mfma16(a1[m], b0[n], acc[m][n]);
            }
        __syncthreads();
    }

    int rbase = bm0 + wr + (g << 2);
    int cb = bn0 + wc + fr;
    if constexpr (EPI == 4) {
        // bias + softplus, store transposed: C[col][row], float4 over i
        #pragma unroll
        for (int m = 0; m < 4; ++m)
            #pragma unroll
            for (int n = 0; n < 4; ++n) {
                int col = cb + n * 16;
                float b_ = aux[col];
                float vv[4];
                #pragma unroll
                for (int i = 0; i < 4; ++i)
                    vv[i] = softplusf_(acc[m][n][i] + b_);
                *(float4*)&C[(size_t)col * ldc + rbase + m * 16] = *(float4*)vv;
            }
    } else {
        #pragma unroll
        for (int m = 0; m < 4; ++m)
            #pragma unroll
            for (int i = 0; i < 4; ++i) {
                int row = rbase + m * 16 + i;
                #pragma unroll
                for (int n = 0; n < 4; ++n) {
                    int col = cb + n * 16;
                    float v = acc[m][n][i];
                    if constexpr (EPI == 3) {
                        if (col < Nb) atomicAdd(&C[(size_t)row * ldc + col], v);
                    } else {
                        if constexpr (EPI == 1) v = softplusf_(v + aux[col]);
                        if constexpr (EPI == 2) v += aux[(size_t)row * ldc + col];
                        C[(size_t)row * ldc + col] = v;
                    }
                }
            }
    }
}

// ---------------- causal depthwise conv1d (K=4) + bias + SiLU ----------------
// Sliding-window: thread = (4 d-channels, 8 consecutive tokens).
// Emits u_h/u_l bf16 [tok][d] (for x_proj) + u_t f32 [d][tok] (for scan; kills
// the separate transpose kernel and 4x tap re-reads).
__global__ __launch_bounds__(256) void k_conv_silu(
    const float* __restrict__ xr, const float* __restrict__ w,
    const float* __restrict__ bconv,
    bf16* __restrict__ uh, bf16* __restrict__ ul, float* __restrict__ u_t)
{
    int idx = blockIdx.x * 256 + threadIdx.x;  // 512 blocks: (TOK/8)*(DI/4)/256
    int dq = idx & 511;
    int ts = idx >> 9;                 // 0..255
    int bb = ts >> 7;
    int t0 = (ts & 127) * 8;
    int dd = dq * 4;

    float4 wrow[4];
    #pragma unroll
    for (int j = 0; j < 4; j++)
        wrow[j] = *(const float4*)&w[(dd + j) * 4];
    float4 bias4 = *(const float4*)&bconv[dd];
    const float bias_[4] = { bias4.x, bias4.y, bias4.z, bias4.w };

    auto ldrow = [&](int t) -> float4 {
        if (t < 0) return make_float4(0.f, 0.f, 0.f, 0.f);
        return *(const float4*)&xr[((size_t)(bb * L_ + t)) * (2 * DI) + dd];
    };
    float4 a = ldrow(t0 - 3), b = ldrow(t0 - 2), c = ldrow(t0 - 1);

    float uout[4][8];                  // [d-j][k]
    #pragma unroll
    for (int k = 0; k < 8; ++k) {
        float4 d4 = ldrow(t0 + k);
        const float as[4] = {a.x, a.y, a.z, a.w};
        const float bs[4] = {b.x, b.y, b.z, b.w};
        const float cs[4] = {c.x, c.y, c.z, c.w};
        const float ds[4] = {d4.x, d4.y, d4.z, d4.w};
        alignas(8) bf16 H[4], Lo[4];
        #pragma unroll
        for (int j = 0; j < 4; ++j) {
            const float* wj = (const float*)&wrow[j];
            float acc = bias_[j];
            acc = fmaf(as[j], wj[0], acc);
            acc = fmaf(bs[j], wj[1], acc);
            acc = fmaf(cs[j], wj[2], acc);
            acc = fmaf(ds[j], wj[3], acc);
            float o = acc * sigmoidf_(acc);
            uout[j][k] = o;
            H[j]  = __float2bfloat16(o);
            Lo[j] = __float2bfloat16(o - __bfloat162float(H[j]));
        }
        size_t base = ((size_t)(bb * L_ + t0 + k)) * DI + dd;
        *(ushort4*)(uh + base) = *(ushort4*)H;
        *(ushort4*)(ul + base) = *(ushort4*)Lo;
        a = b; b = c; c = d4;
    }
    // u_t: per d-row, 8 consecutive f32 (two float4, t0 is 8-aligned)
    #pragma unroll
    for (int j = 0; j < 4; ++j) {
        size_t tb = (size_t)(dd + j) * TOK + bb * L_ + t0;
        *(float4*)&u_t[tb]     = make_float4(uout[j][0], uout[j][1], uout[j][2], uout[j][3]);
        *(float4*)&u_t[tb + 4] = make_float4(uout[j][4], uout[j][5], uout[j][6], uout[j][7]);
    }
}

// ---------------- chunked selective scan (transposed inputs) ----------------
// Pass A: local scan -> P (prod dA = exp(A*sum_dl)), S (end state).
__global__ __launch_bounds__(256) void k_scan_part(
    const float* __restrict__ delta_t, const float* __restrict__ u_t,
    const float* __restrict__ bc_t,    const float* __restrict__ A_log,
    float* __restrict__ P, float* __restrict__ S)
{
    int bx = blockIdx.x;               // 2048
    int c = bx & (NC - 1);
    int rest = bx >> 5;
    int b = rest >> 5;
    int d0 = (rest & 31) << 6;
    int t = threadIdx.x;
    int dl_ = t >> 2, q = t & 3;
    int d = d0 + dl_;

    float A_dn[4];
    #pragma unroll
    for (int j = 0; j < 4; ++j)
        A_dn[j] = -__expf(A_log[d * NS + q * 4 + j]);

    float s[4] = {};
    float dsum = 0.f;
    int tokb = b * L_ + c * (L_ / NC);
    const float* dbase = delta_t + (size_t)d * TOK + tokb;
    const float* ubase = u_t + (size_t)d * TOK + tokb;
    const float* Bbase = bc_t + (size_t)(q * 4) * TOK + tokb;

    for (int g = 0; g < (L_ / NC) / 4; ++g) {
        float4 dl4 = *(const float4*)(dbase + g * 4);
        float4 uu4 = *(const float4*)(ubase + g * 4);
        float Bm_[4][4];
        #pragma unroll
        for (int j = 0; j < 4; ++j) {
            float4 bv = *(const float4*)(Bbase + (size_t)j * TOK + g * 4);
            Bm_[j][0] = bv.x; Bm_[j][1] = bv.y; Bm_[j][2] = bv.z; Bm_[j][3] = bv.w;
        }
        const float dls[4] = {dl4.x, dl4.y, dl4.z, dl4.w};
        const float uus[4] = {uu4.x, uu4.y, uu4.z, uu4.w};
        #pragma unroll
        for (int k = 0; k < 4; ++k) {
            float dlu = dls[k] * uus[k];
            dsum += dls[k];
            #pragma unroll
            for (int j = 0; j < 4; ++j) {
                float e = __expf(dls[k] * A_dn[j]);
                s[j] = fmaf(e, s[j], dlu * Bm_[j][k]);
            }
        }
    }
    float p[4];
    #pragma unroll
    for (int j = 0; j < 4; ++j)
        p[j] = __expf(A_dn[j] * dsum);
    size_t o = (((size_t)(b * NC + c) * DI) + d) * NS + q * 4;
    *(float4*)&P[o] = *(float4*)p;
    *(float4*)&S[o] = *(float4*)s;
}

// Pass B: sequential chunk combine; init written IN-PLACE into S.
__global__ __launch_bounds__(256) void k_scan_comb(
    const float* __restrict__ P, float* __restrict__ S)
{
    int idx = blockIdx.x * 256 + threadIdx.x;  // 65536
    int n = idx & 15;
    int d = (idx >> 4) & (DI - 1);
    int b = idx >> 15;
    float carry = 0.f;
    #pragma unroll
    for (int c = 0; c < NC; ++c) {
        size_t o = (((size_t)(b * NC + c) * DI) + d) * NS + n;
        float Pv = P[o], Sv = S[o];
        S[o] = carry;
        carry = fmaf(Pv, carry, Sv);
    }
}

// Pass C: re-scan with init; quad allreduce; each lane writes tok0+q.
__global__ __launch_bounds__(256) void k_scan_y(
    const float* __restrict__ delta_t, const float* __restrict__ u_t,
    const float* __restrict__ bc_t,    const float* __restrict__ xr,
    const float* __restrict__ A_log,   const float* __restrict__ Dp,
    const float* __restrict__ init, bf16* __restrict__ y)
{
    int bx = blockIdx.x;               // 2048
    int c = bx & (NC - 1);
    int rest = bx >> 5;
    int b = rest >> 5;
    int d0 = (rest & 31) << 6;
    int t = threadIdx.x;
    int dl_ = t >> 2, q = t & 3;
    int d = d0 + dl_;

    float A_dn[4];
    #pragma unroll
    for (int j = 0; j < 4; ++j)
        A_dn[j] = -__expf(A_log[d * NS + q * 4 + j]);
    float Dd = Dp[d];

    size_t o = (((size_t)(b * NC + c) * DI) + d) * NS + q * 4;
    float4 s4 = *(const float4*)&init[o];
    float s[4] = {s4.x, s4.y, s4.z, s4.w};

    int tokb = b * L_ + c * (L_ / NC);
    const float* dbase = delta_t + (size_t)d * TOK + tokb;
    const float* ubase = u_t + (size_t)d * TOK + tokb;
    const float* Bbase = bc_t + (size_t)(q * 4) * TOK + tokb;
    const float* Cbase = bc_t + (size_t)(16 + q * 4) * TOK + tokb;

    for (int g = 0; g < (L_ / NC) / 4; ++g) {
        int tok0 = tokb + g * 4;
        float4 dl4 = *(const float4*)(dbase + g * 4);
        float4 uu4 = *(const float4*)(ubase + g * 4);
        float Bm_[4][4], Cm_[4][4];
        #pragma unroll
        for (int j = 0; j < 4; ++j) {
            float4 bv = *(const float4*)(Bbase + (size_t)j * TOK + g * 4);
            float4 cv = *(const float4*)(Cbase + (size_t)j * TOK + g * 4);
            Bm_[j][0] = bv.x; Bm_[j][1] = bv.y; Bm_[j][2] = bv.z; Bm_[j][3] = bv.w;
            Cm_[j][0] = cv.x; Cm_[j][1] = cv.y; Cm_[j][2] = cv.z; Cm_[j][3] = cv.w;
        }
        const float dls[4] = {dl4.x, dl4.y, dl4.z, dl4.w};
        const float uus[4] = {uu4.x, uu4.y, uu4.z, uu4.w};
        float py[4];
        #pragma unroll
        for (int k = 0; k < 4; ++k) {
            float dlu = dls[k] * uus[k];
            float a_ = 0.f;
            #pragma unroll
            for (int j = 0; j < 4; ++j) {
                float e = __expf(dls[k] * A_dn[j]);
                s[j] = fmaf(e, s[j], dlu * Bm_[j][k]);
                a_ = fmaf(s[j], Cm_[j][k], a_);
            }
            py[k] = a_;
        }
        #pragma unroll
        for (int k = 0; k < 4; ++k) {
            py[k] += __shfl_xor(py[k], 1);
            py[k] += __shfl_xor(py[k], 2);
        }
        float py_q = py[0], uu_q = uus[0];
        py_q = (q == 1) ? py[1] : py_q;  uu_q = (q == 1) ? uus[1] : uu_q;
        py_q = (q == 2) ? py[2] : py_q;  uu_q = (q == 2) ? uus[2] : uu_q;
        py_q = (q == 3) ? py[3] : py_q;  uu_q = (q == 3) ? uus[3] : uu_q;
        int tok = tok0 + q;
        float rr = xr[(size_t)tok * (2 * DI) + DI + d];
        float yv = fmaf(uu_q, Dd, py_q) * (rr * sigmoidf_(rr));
        y[(size_t)tok * DI + d] = __float2bfloat16(yv);
    }
}

extern "C" void kernel_launch(void* const* d_in, const int* in_sizes, int n_in,
                              void* d_out, int out_size, void* d_ws, size_t ws_size,
                              hipStream_t stream)
{
    const float* x       = (const float*)d_in[0];
    const float* norm_w  = (const float*)d_in[1];
    const float* in_proj = (const float*)d_in[2];
    const float* conv_w  = (const float*)d_in[3];
    const float* conv_b  = (const float*)d_in[4];
    const float* x_proj  = (const float*)d_in[5];
    const float* dt_w    = (const float*)d_in[6];
    const float* dt_b    = (const float*)d_in[7];
    const float* A_log   = (const float*)d_in[8];
    const float* Dp      = (const float*)d_in[9];
    const float* out_w   = (const float*)d_in[10];
    float* out = (float*)d_out;

    // ---- workspace layout (lifetime-aliased, peak ~83.25 MB) ----
    constexpr size_t MB = 1u << 20;
    constexpr size_t KB = 1u << 10;
    char* Wb = (char*)d_ws;
    float* xr      = (float*)(Wb + 0);                  // 32MB  in_proj..scan_y
    bf16*  h_h     = (bf16*) (Wb + 32 * MB);            // 4MB   rms..in_proj
    bf16*  h_l     = (bf16*) (Wb + 36 * MB);            // 4MB
    bf16*  u_h     = (bf16*) (Wb + 32 * MB);            // 8MB   conv..x_proj (over h)
    bf16*  u_l     = (bf16*) (Wb + 40 * MB);            // 8MB
    float* Pbuf    = (float*)(Wb + 32 * MB);            // 8MB   scan_part..comb (over u_h)
    float* Sbuf    = (float*)(Wb + 40 * MB);            // 8MB   scan_part..scan_y (over u_l)
    bf16*  y_h     = (bf16*) (Wb + 32 * MB);            // 8MB   scan_y..out_proj (over dead P)
    float* u_t     = (float*)(Wb + 48 * MB);            // 16MB  conv..scan_y
    bf16*  wo_h    = (bf16*) (Wb + 48 * MB);            // 4MB   split_wo (after scan_y)
    bf16*  wo_l    = (bf16*) (Wb + 52 * MB);            // 4MB
    bf16*  wi_h    = (bf16*) (Wb + 64 * MB);            // 8MB   split..in_proj
    bf16*  wi_l    = (bf16*) (Wb + 72 * MB);            // 8MB
    float* delta_t = (float*)(Wb + 64 * MB);            // 16MB  dt_proj..scan_y (over wi)
    float* xdbl    = (float*)(Wb + 80 * MB);            // 768KB
    bf16*  xp_h    = (bf16*) (Wb + 80 * MB + 768 * KB); // 512KB
    bf16*  xp_l    = (bf16*) (Wb + 81 * MB + 256 * KB); // 512KB
    bf16*  xdbl_h  = (bf16*) (Wb + 81 * MB + 768 * KB); // 384KB
    bf16*  xdbl_l  = (bf16*) (Wb + 82 * MB + 128 * KB); // 384KB
    float* bc_t    = (float*)(Wb + 82 * MB + 512 * KB); // 256KB
    bf16*  dtw_h   = (bf16*) (Wb + 82 * MB + 768 * KB); // 256KB
    bf16*  dtw_l   = (bf16*) (Wb + 83 * MB);            // 256KB

    // 1) RMSNorm -> h hi/lo
    k_rmsnorm<<<TOK, 256, 0, stream>>>(x, norm_w, h_h, h_l);
    // 2) split in_proj weights
    k_split<<<4096, 256, 0, stream>>>(in_proj, wi_h, wi_l, (2 * DI * DM) / 4);
    // 3) in_proj: [2048,1024] x [4096,1024]^T -> xr  (bf16x3)
    k_gemm_bf16<2, 0><<<dim3(32, 16, 1), 256, 0, stream>>>(
        h_h, h_l, DM, wi_h, wi_l, DM, xr, 2 * DI, nullptr, TOK, 2 * DI, DM);
    // 4) sliding-window conv + SiLU -> u_h/u_l bf16 [tok][d] + u_t f32 [d][tok]
    k_conv_silu<<<512, 256, 0, stream>>>(xr, conv_w, conv_b, u_h, u_l, u_t);
    // 5) pad-split x_proj weights
    k_split_pad<<<256, 256, 0, stream>>>(x_proj, xp_h, xp_l);
    // 6) x_proj: split-K=32, bf16x3, atomic f32 -> xdbl [2048,96]
    hipMemsetAsync(xdbl, 0, (size_t)TOK * 96 * sizeof(float), stream);
    k_gemm_bf16<2, 3><<<dim3(1, 16, 32), 256, 0, stream>>>(
        u_h, u_l, DI, xp_h, xp_l, DI, xdbl, 96, nullptr, TOK, 96, DI / 32);
    // 7) fused xdbl split + B/C transpose
    k_xdbl_post<<<TOK, 128, 0, stream>>>(xdbl, xdbl_h, xdbl_l, bc_t);
    // 8) split dt weights
    k_split<<<128, 256, 0, stream>>>(dt_w, dtw_h, dtw_l, (DI * DTR) / 4);
    // 9) dt_proj + softplus -> delta_t [DI][TOK] (transposed epilogue; over dead wi)
    k_gemm_bf16<2, 4><<<dim3(16, 16, 1), 256, 0, stream>>>(
        xdbl_h, xdbl_l, 96, dtw_h, dtw_l, DTR, delta_t, TOK, dt_b, TOK, DI, DTR);
    // 10) chunked scan (NC=32)
    k_scan_part<<<B_ * NC * (DI / 64), 256, 0, stream>>>(
        delta_t, u_t, bc_t, A_log, Pbuf, Sbuf);
    k_scan_comb<<<256, 256, 0, stream>>>(Pbuf, Sbuf);
    k_scan_y<<<B_ * NC * (DI / 64), 256, 0, stream>>>(
        delta_t, u_t, bc_t, xr, A_log, Dp, Sbuf, y_h);
    // 11) split out_proj weights (u_t dead after scan_y)
    k_split<<<2048, 256, 0, stream>>>(out_w, wo_h, wo_l, (DM * DI) / 4);
    // 12) out_proj: seed out with residual x, then split-K=4 atomic bf16x2
    hipMemcpyAsync(out, x, (size_t)TOK * DM * sizeof(float),
                   hipMemcpyDeviceToDevice, stream);
    k_gemm_bf16<1, 3><<<dim3(8, 16, 4), 256, 0, stream>>>(
        y_h, nullptr, DI, wo_h, wo_l, DI, out, DM, nullptr, TOK, DM, DI / 4);
}

// Round 8
// 335.628 us; speedup vs baseline: 1.1435x; 1.0969x over previous
//
#include <hip/hip_runtime.h>
#include <hip/hip_bf16.h>
#include <math.h>

constexpr int B_   = 2;
constexpr int L_   = 1024;
constexpr int DM   = 1024;
constexpr int DI   = 2048;
constexpr int NS   = 16;
constexpr int DTR  = 64;
constexpr int TOK  = B_ * L_;
constexpr int NC   = 32;      // scan chunks; serial length 32
constexpr int ZX   = 16;      // x_proj split-K slices
constexpr int ZO   = 4;       // out_proj split-K slices

typedef __attribute__((ext_vector_type(8))) short short8;
typedef __attribute__((ext_vector_type(4))) float f32x4;
using bf16 = __hip_bfloat16;

__device__ __forceinline__ float sigmoidf_(float v) {
    return 1.f / (1.f + __expf(-v));
}
__device__ __forceinline__ float softplusf_(float v) {
    return fmaxf(v, 0.f) + __logf(1.f + __expf(-fabsf(v)));
}

__device__ __forceinline__ f32x4 mfma16(short8 a, short8 b, f32x4 c) {
    return __builtin_amdgcn_mfma_f32_16x16x32_bf16(a, b, c, 0, 0, 0);
}

// ---------------- RMSNorm -> bf16 hi/lo split ----------------
__global__ __launch_bounds__(256) void k_rmsnorm(
    const float* __restrict__ x, const float* __restrict__ w,
    bf16* __restrict__ hh, bf16* __restrict__ hl)
{
    int row = blockIdx.x;
    const float4* xrp = (const float4*)(x + (size_t)row * DM);
    float4 v = xrp[threadIdx.x];
    float ss = v.x*v.x + v.y*v.y + v.z*v.z + v.w*v.w;
    #pragma unroll
    for (int m = 32; m >= 1; m >>= 1) ss += __shfl_xor(ss, m);
    __shared__ float acc[4];
    int wid = threadIdx.x >> 6, lane = threadIdx.x & 63;
    if (lane == 0) acc[wid] = ss;
    __syncthreads();
    float tot = acc[0] + acc[1] + acc[2] + acc[3];
    float sc = rsqrtf(tot * (1.f / DM) + 1e-5f);
    float4 wv = ((const float4*)w)[threadIdx.x];
    float o[4] = { v.x*sc*wv.x, v.y*sc*wv.y, v.z*sc*wv.z, v.w*sc*wv.w };
    alignas(8) bf16 H[4], Lo[4];
    #pragma unroll
    for (int j = 0; j < 4; ++j) {
        H[j]  = __float2bfloat16(o[j]);
        Lo[j] = __float2bfloat16(o[j] - __bfloat162float(H[j]));
    }
    size_t base = (size_t)row * DM + threadIdx.x * 4;
    *(ushort4*)(hh + base) = *(ushort4*)H;
    *(ushort4*)(hl + base) = *(ushort4*)Lo;
}

// ---------------- fp32 -> bf16 hi/lo split (wo, after scan) ----------------
__global__ __launch_bounds__(256) void k_split(
    const float* __restrict__ s, bf16* __restrict__ hi, bf16* __restrict__ lo, int n4)
{
    int i = blockIdx.x * 256 + threadIdx.x;
    if (i >= n4) return;
    float4 v = ((const float4*)s)[i];
    float f[4] = { v.x, v.y, v.z, v.w };
    alignas(8) bf16 H[4], Lo[4];
    #pragma unroll
    for (int j = 0; j < 4; ++j) {
        H[j]  = __float2bfloat16(f[j]);
        Lo[j] = __float2bfloat16(f[j] - __bfloat162float(H[j]));
    }
    *(ushort4*)(hi + (size_t)i * 4) = *(ushort4*)H;
    *(ushort4*)(lo + (size_t)i * 4) = *(ushort4*)Lo;
}

// ---- fused weight split: in_proj + dt_w + x_proj(pad to 128 rows) ----
constexpr int N4_WI  = (2 * DI * DM) / 4;   // 1048576
constexpr int N4_DTW = (DI * DTR) / 4;      // 32768
constexpr int N4_XP  = (128 * DI) / 4;      // 65536
__global__ __launch_bounds__(256) void k_split_all(
    const float* __restrict__ wi, const float* __restrict__ dtw,
    const float* __restrict__ xp,
    bf16* __restrict__ wi_h, bf16* __restrict__ wi_l,
    bf16* __restrict__ dtw_h, bf16* __restrict__ dtw_l,
    bf16* __restrict__ xp_h, bf16* __restrict__ xp_l)
{
    int i = blockIdx.x * 256 + threadIdx.x;
    const float* src; bf16 *hi, *lo; int j; bool zero = false;
    if (i < N4_WI)                  { j = i;                    src = wi;  hi = wi_h;  lo = wi_l; }
    else if (i < N4_WI + N4_DTW)    { j = i - N4_WI;            src = dtw; hi = dtw_h; lo = dtw_l; }
    else if (i < N4_WI + N4_DTW + N4_XP) {
        j = i - N4_WI - N4_DTW; src = xp; hi = xp_h; lo = xp_l;
        zero = (j >> 9) >= 96;      // pad rows 96..127
    } else return;
    float f[4] = {0.f, 0.f, 0.f, 0.f};
    if (!zero) {
        float4 v = ((const float4*)src)[j];
        f[0] = v.x; f[1] = v.y; f[2] = v.z; f[3] = v.w;
    }
    alignas(8) bf16 H[4], Lo[4];
    #pragma unroll
    for (int k = 0; k < 4; ++k) {
        H[k]  = __float2bfloat16(f[k]);
        Lo[k] = __float2bfloat16(f[k] - __bfloat162float(H[k]));
    }
    *(ushort4*)(hi + (size_t)j * 4) = *(ushort4*)H;
    *(ushort4*)(lo + (size_t)j * 4) = *(ushort4*)Lo;
}

// ---- x_proj partial reduce: sum 16 slices + hi/lo split + B/C transpose ----
__global__ __launch_bounds__(192) void k_xdbl_reduce(
    const float* __restrict__ part, bf16* __restrict__ hi, bf16* __restrict__ lo,
    float* __restrict__ bc_t)
{
    int t = threadIdx.x;               // 0..191 = 2 tokens x 96 cols
    int tok = blockIdx.x * 2 + (t >= 96 ? 1 : 0);
    int col = (t >= 96) ? t - 96 : t;
    float v = 0.f;
    #pragma unroll
    for (int z = 0; z < ZX; ++z)
        v += part[((size_t)z * TOK + tok) * 96 + col];
    bf16 H = __float2bfloat16(v);
    hi[(size_t)tok * 96 + col] = H;
    lo[(size_t)tok * 96 + col] = __float2bfloat16(v - __bfloat162float(H));
    if (col >= 64) bc_t[(size_t)(col - 64) * TOK + tok] = v;
}

// ---- out_proj partial reduce + residual ----
__global__ __launch_bounds__(256) void k_out_reduce(
    const float* __restrict__ part, const float* __restrict__ x,
    float* __restrict__ out)
{
    int i = blockIdx.x * 256 + threadIdx.x;   // TOK*DM/4
    float4 a = ((const float4*)x)[i];
    #pragma unroll
    for (int z = 0; z < ZO; ++z) {
        float4 p = ((const float4*)(part + (size_t)z * TOK * DM))[i];
        a.x += p.x; a.y += p.y; a.z += p.z; a.w += p.w;
    }
    ((float4*)out)[i] = a;
}

// ---------------- bf16 split-GEMM via MFMA ----------------
// C[M,N] = A[M,K] * B[N,K]^T; A has NA parts, B has 2.
// EPI: 0 plain f32 store,
//      4 bias+softplus + TRANSPOSED float4 store (C is [N][ldc]),
//      5 split-K partial store: C + z*M*Nb, row-stride Nb, masked col<Nb.
__device__ __forceinline__ void stage_tile(const bf16* src, int ld, bf16* lds, int lane)
{
    #pragma unroll
    for (int j = 0; j < 8; ++j) {
        int c = (j << 6) + lane;
        int r = c >> 2;
        int g = (c & 3) ^ ((r >> 1) & 3);
        __builtin_amdgcn_global_load_lds(
            (const __attribute__((address_space(1))) unsigned int*)(src + (size_t)r * ld + (g << 3)),
            (__attribute__((address_space(3))) unsigned int*)(lds + (j << 9)),
            16, 0, 0);
    }
}

template<int NA, int EPI>
__global__ __launch_bounds__(256) void k_gemm_bf16(
    const bf16* __restrict__ Ah, const bf16* __restrict__ Al, int lda,
    const bf16* __restrict__ Bh, const bf16* __restrict__ Bl, int ldb,
    float* __restrict__ C, int ldc,
    const float* __restrict__ aux,      // bias (EPI=4)
    int M, int Nb, int Kc)              // Kc = K count per z-slice
{
    __shared__ alignas(1024) bf16 sA[2][NA][128 * 32];
    __shared__ alignas(1024) bf16 sB[2][2][128 * 32];

    int tid = threadIdx.x, lane = tid & 63, wv = tid >> 6;
    int bm0 = blockIdx.y * 128, bn0 = blockIdx.x * 128;
    int kbase = blockIdx.z * Kc;
    int nkt = Kc >> 5;

    const bf16* Abase_h = Ah + (size_t)bm0 * lda + kbase;
    const bf16* Abase_l = (NA == 2) ? (Al + (size_t)bm0 * lda + kbase) : nullptr;
    const bf16* Bbase_h = Bh + (size_t)bn0 * ldb + kbase;
    const bf16* Bbase_l = Bl + (size_t)bn0 * ldb + kbase;

    auto stage_all = [&](int buf, int kt) {
        int k0 = kt << 5;
        if constexpr (NA == 2) {
            if      (wv == 0) stage_tile(Abase_h + k0, lda, &sA[buf][0][0], lane);
            else if (wv == 1) stage_tile(Abase_l + k0, lda, &sA[buf][1][0], lane);
            else if (wv == 2) stage_tile(Bbase_h + k0, ldb, &sB[buf][0][0], lane);
            else              stage_tile(Bbase_l + k0, ldb, &sB[buf][1][0], lane);
        } else {
            if      (wv == 0) stage_tile(Abase_h + k0, lda, &sA[buf][0][0], lane);
            else if (wv == 1) stage_tile(Bbase_h + k0, ldb, &sB[buf][0][0], lane);
            else if (wv == 2) stage_tile(Bbase_l + k0, ldb, &sB[buf][1][0], lane);
        }
    };
    auto frag = [&](const bf16* t, int r, int g) -> short8 {
        int c = (r << 2) + (g ^ ((r >> 1) & 3));
        return *(const short8*)(t + (c << 3));
    };

    int wr = (wv >> 1) << 6;
    int wc = (wv & 1) << 6;
    int fr = lane & 15, g = lane >> 4;

    f32x4 acc[4][4] = {};

    stage_all(0, 0);
    __syncthreads();
    for (int kt = 0; kt < nkt; ++kt) {
        int cur = kt & 1;
        if (kt + 1 < nkt) stage_all(cur ^ 1, kt + 1);
        short8 a0[4], a1[4], b0[4], b1[4];
        #pragma unroll
        for (int m = 0; m < 4; ++m) {
            a0[m] = frag(&sA[cur][0][0], wr + m * 16 + fr, g);
            if constexpr (NA == 2) a1[m] = frag(&sA[cur][NA - 1][0], wr + m * 16 + fr, g);
        }
        #pragma unroll
        for (int n = 0; n < 4; ++n) {
            b0[n] = frag(&sB[cur][0][0], wc + n * 16 + fr, g);
            b1[n] = frag(&sB[cur][1][0], wc + n * 16 + fr, g);
        }
        #pragma unroll
        for (int m = 0; m < 4; ++m)
            #pragma unroll
            for (int n = 0; n < 4; ++n) {
                acc[m][n] = mfma16(a0[m], b0[n], acc[m][n]);
                acc[m][n] = mfma16(a0[m], b1[n], acc[m][n]);
                if constexpr (NA == 2) acc[m][n] = mfma16(a1[m], b0[n], acc[m][n]);
            }
        __syncthreads();
    }

    int rbase = bm0 + wr + (g << 2);
    int cb = bn0 + wc + fr;
    if constexpr (EPI == 4) {
        // bias + softplus, store transposed: C[col][row], float4 over i
        #pragma unroll
        for (int m = 0; m < 4; ++m)
            #pragma unroll
            for (int n = 0; n < 4; ++n) {
                int col = cb + n * 16;
                float b_ = aux[col];
                float vv[4];
                #pragma unroll
                for (int i = 0; i < 4; ++i)
                    vv[i] = softplusf_(acc[m][n][i] + b_);
                *(float4*)&C[(size_t)col * ldc + rbase + m * 16] = *(float4*)vv;
            }
    } else if constexpr (EPI == 5) {
        float* Cz = C + (size_t)blockIdx.z * M * Nb;
        #pragma unroll
        for (int m = 0; m < 4; ++m)
            #pragma unroll
            for (int i = 0; i < 4; ++i) {
                int row = rbase + m * 16 + i;
                #pragma unroll
                for (int n = 0; n < 4; ++n) {
                    int col = cb + n * 16;
                    if (col < Nb)
                        Cz[(size_t)row * Nb + col] = acc[m][n][i];
                }
            }
    } else {
        #pragma unroll
        for (int m = 0; m < 4; ++m)
            #pragma unroll
            for (int i = 0; i < 4; ++i) {
                int row = rbase + m * 16 + i;
                #pragma unroll
                for (int n = 0; n < 4; ++n)
                    C[(size_t)row * ldc + cb + n * 16] = acc[m][n][i];
            }
    }
}

// ---------------- causal depthwise conv1d (K=4) + bias + SiLU ----------------
// Sliding-window: thread = (4 d-channels, 8 consecutive tokens).
// Emits u_h/u_l bf16 [tok][d] (for x_proj) + u_t f32 [d][tok] (for scan).
__global__ __launch_bounds__(256) void k_conv_silu(
    const float* __restrict__ xr, const float* __restrict__ w,
    const float* __restrict__ bconv,
    bf16* __restrict__ uh, bf16* __restrict__ ul, float* __restrict__ u_t)
{
    int idx = blockIdx.x * 256 + threadIdx.x;  // 512 blocks
    int dq = idx & 511;
    int ts = idx >> 9;                 // 0..255
    int bb = ts >> 7;
    int t0 = (ts & 127) * 8;
    int dd = dq * 4;

    float4 wrow[4];
    #pragma unroll
    for (int j = 0; j < 4; j++)
        wrow[j] = *(const float4*)&w[(dd + j) * 4];
    float4 bias4 = *(const float4*)&bconv[dd];
    const float bias_[4] = { bias4.x, bias4.y, bias4.z, bias4.w };

    auto ldrow = [&](int t) -> float4 {
        if (t < 0) return make_float4(0.f, 0.f, 0.f, 0.f);
        return *(const float4*)&xr[((size_t)(bb * L_ + t)) * (2 * DI) + dd];
    };
    float4 a = ldrow(t0 - 3), b = ldrow(t0 - 2), c = ldrow(t0 - 1);

    float uout[4][8];
    #pragma unroll
    for (int k = 0; k < 8; ++k) {
        float4 d4 = ldrow(t0 + k);
        const float as[4] = {a.x, a.y, a.z, a.w};
        const float bs[4] = {b.x, b.y, b.z, b.w};
        const float cs[4] = {c.x, c.y, c.z, c.w};
        const float ds[4] = {d4.x, d4.y, d4.z, d4.w};
        alignas(8) bf16 H[4], Lo[4];
        #pragma unroll
        for (int j = 0; j < 4; ++j) {
            const float* wj = (const float*)&wrow[j];
            float acc = bias_[j];
            acc = fmaf(as[j], wj[0], acc);
            acc = fmaf(bs[j], wj[1], acc);
            acc = fmaf(cs[j], wj[2], acc);
            acc = fmaf(ds[j], wj[3], acc);
            float o = acc * sigmoidf_(acc);
            uout[j][k] = o;
            H[j]  = __float2bfloat16(o);
            Lo[j] = __float2bfloat16(o - __bfloat162float(H[j]));
        }
        size_t base = ((size_t)(bb * L_ + t0 + k)) * DI + dd;
        *(ushort4*)(uh + base) = *(ushort4*)H;
        *(ushort4*)(ul + base) = *(ushort4*)Lo;
        a = b; b = c; c = d4;
    }
    #pragma unroll
    for (int j = 0; j < 4; ++j) {
        size_t tb = (size_t)(dd + j) * TOK + bb * L_ + t0;
        *(float4*)&u_t[tb]     = make_float4(uout[j][0], uout[j][1], uout[j][2], uout[j][3]);
        *(float4*)&u_t[tb + 4] = make_float4(uout[j][4], uout[j][5], uout[j][6], uout[j][7]);
    }
}

// ---------------- chunked selective scan (transposed inputs) ----------------
__global__ __launch_bounds__(256) void k_scan_part(
    const float* __restrict__ delta_t, const float* __restrict__ u_t,
    const float* __restrict__ bc_t,    const float* __restrict__ A_log,
    float* __restrict__ P, float* __restrict__ S)
{
    int bx = blockIdx.x;               // 2048
    int c = bx & (NC - 1);
    int rest = bx >> 5;
    int b = rest >> 5;
    int d0 = (rest & 31) << 6;
    int t = threadIdx.x;
    int dl_ = t >> 2, q = t & 3;
    int d = d0 + dl_;

    float A_dn[4];
    #pragma unroll
    for (int j = 0; j < 4; ++j)
        A_dn[j] = -__expf(A_log[d * NS + q * 4 + j]);

    float s[4] = {};
    float dsum = 0.f;
    int tokb = b * L_ + c * (L_ / NC);
    const float* dbase = delta_t + (size_t)d * TOK + tokb;
    const float* ubase = u_t + (size_t)d * TOK + tokb;
    const float* Bbase = bc_t + (size_t)(q * 4) * TOK + tokb;

    for (int g = 0; g < (L_ / NC) / 4; ++g) {
        float4 dl4 = *(const float4*)(dbase + g * 4);
        float4 uu4 = *(const float4*)(ubase + g * 4);
        float Bm_[4][4];
        #pragma unroll
        for (int j = 0; j < 4; ++j) {
            float4 bv = *(const float4*)(Bbase + (size_t)j * TOK + g * 4);
            Bm_[j][0] = bv.x; Bm_[j][1] = bv.y; Bm_[j][2] = bv.z; Bm_[j][3] = bv.w;
        }
        const float dls[4] = {dl4.x, dl4.y, dl4.z, dl4.w};
        const float uus[4] = {uu4.x, uu4.y, uu4.z, uu4.w};
        #pragma unroll
        for (int k = 0; k < 4; ++k) {
            float dlu = dls[k] * uus[k];
            dsum += dls[k];
            #pragma unroll
            for (int j = 0; j < 4; ++j) {
                float e = __expf(dls[k] * A_dn[j]);
                s[j] = fmaf(e, s[j], dlu * Bm_[j][k]);
            }
        }
    }
    float p[4];
    #pragma unroll
    for (int j = 0; j < 4; ++j)
        p[j] = __expf(A_dn[j] * dsum);
    size_t o = (((size_t)(b * NC + c) * DI) + d) * NS + q * 4;
    *(float4*)&P[o] = *(float4*)p;
    *(float4*)&S[o] = *(float4*)s;
}

__global__ __launch_bounds__(256) void k_scan_comb(
    const float* __restrict__ P, float* __restrict__ S)
{
    int idx = blockIdx.x * 256 + threadIdx.x;  // 65536
    int n = idx & 15;
    int d = (idx >> 4) & (DI - 1);
    int b = idx >> 15;
    float carry = 0.f;
    #pragma unroll
    for (int c = 0; c < NC; ++c) {
        size_t o = (((size_t)(b * NC + c) * DI) + d) * NS + n;
        float Pv = P[o], Sv = S[o];
        S[o] = carry;
        carry = fmaf(Pv, carry, Sv);
    }
}

__global__ __launch_bounds__(256) void k_scan_y(
    const float* __restrict__ delta_t, const float* __restrict__ u_t,
    const float* __restrict__ bc_t,    const float* __restrict__ xr,
    const float* __restrict__ A_log,   const float* __restrict__ Dp,
    const float* __restrict__ init, bf16* __restrict__ y)
{
    int bx = blockIdx.x;               // 2048
    int c = bx & (NC - 1);
    int rest = bx >> 5;
    int b = rest >> 5;
    int d0 = (rest & 31) << 6;
    int t = threadIdx.x;
    int dl_ = t >> 2, q = t & 3;
    int d = d0 + dl_;

    float A_dn[4];
    #pragma unroll
    for (int j = 0; j < 4; ++j)
        A_dn[j] = -__expf(A_log[d * NS + q * 4 + j]);
    float Dd = Dp[d];

    size_t o = (((size_t)(b * NC + c) * DI) + d) * NS + q * 4;
    float4 s4 = *(const float4*)&init[o];
    float s[4] = {s4.x, s4.y, s4.z, s4.w};

    int tokb = b * L_ + c * (L_ / NC);
    const float* dbase = delta_t + (size_t)d * TOK + tokb;
    const float* ubase = u_t + (size_t)d * TOK + tokb;
    const float* Bbase = bc_t + (size_t)(q * 4) * TOK + tokb;
    const float* Cbase = bc_t + (size_t)(16 + q * 4) * TOK + tokb;

    for (int g = 0; g < (L_ / NC) / 4; ++g) {
        int tok0 = tokb + g * 4;
        float4 dl4 = *(const float4*)(dbase + g * 4);
        float4 uu4 = *(const float4*)(ubase + g * 4);
        float Bm_[4][4], Cm_[4][4];
        #pragma unroll
        for (int j = 0; j < 4; ++j) {
            float4 bv = *(const float4*)(Bbase + (size_t)j * TOK + g * 4);
            float4 cv = *(const float4*)(Cbase + (size_t)j * TOK + g * 4);
            Bm_[j][0] = bv.x; Bm_[j][1] = bv.y; Bm_[j][2] = bv.z; Bm_[j][3] = bv.w;
            Cm_[j][0] = cv.x; Cm_[j][1] = cv.y; Cm_[j][2] = cv.z; Cm_[j][3] = cv.w;
        }
        const float dls[4] = {dl4.x, dl4.y, dl4.z, dl4.w};
        const float uus[4] = {uu4.x, uu4.y, uu4.z, uu4.w};
        float py[4];
        #pragma unroll
        for (int k = 0; k < 4; ++k) {
            float dlu = dls[k] * uus[k];
            float a_ = 0.f;
            #pragma unroll
            for (int j = 0; j < 4; ++j) {
                float e = __expf(dls[k] * A_dn[j]);
                s[j] = fmaf(e, s[j], dlu * Bm_[j][k]);
                a_ = fmaf(s[j], Cm_[j][k], a_);
            }
            py[k] = a_;
        }
        #pragma unroll
        for (int k = 0; k < 4; ++k) {
            py[k] += __shfl_xor(py[k], 1);
            py[k] += __shfl_xor(py[k], 2);
        }
        float py_q = py[0], uu_q = uus[0];
        py_q = (q == 1) ? py[1] : py_q;  uu_q = (q == 1) ? uus[1] : uu_q;
        py_q = (q == 2) ? py[2] : py_q;  uu_q = (q == 2) ? uus[2] : uu_q;
        py_q = (q == 3) ? py[3] : py_q;  uu_q = (q == 3) ? uus[3] : uu_q;
        int tok = tok0 + q;
        float rr = xr[(size_t)tok * (2 * DI) + DI + d];
        float yv = fmaf(uu_q, Dd, py_q) * (rr * sigmoidf_(rr));
        y[(size_t)tok * DI + d] = __float2bfloat16(yv);
    }
}

extern "C" void kernel_launch(void* const* d_in, const int* in_sizes, int n_in,
                              void* d_out, int out_size, void* d_ws, size_t ws_size,
                              hipStream_t stream)
{
    const float* x       = (const float*)d_in[0];
    const float* norm_w  = (const float*)d_in[1];
    const float* in_proj = (const float*)d_in[2];
    const float* conv_w  = (const float*)d_in[3];
    const float* conv_b  = (const float*)d_in[4];
    const float* x_proj  = (const float*)d_in[5];
    const float* dt_w    = (const float*)d_in[6];
    const float* dt_b    = (const float*)d_in[7];
    const float* A_log   = (const float*)d_in[8];
    const float* Dp      = (const float*)d_in[9];
    const float* out_w   = (const float*)d_in[10];
    float* out = (float*)d_out;

    // ---- workspace layout (lifetime-aliased, peak ~82.5 MB) ----
    constexpr size_t MB = 1u << 20;
    constexpr size_t KB = 1u << 10;
    char* Wb = (char*)d_ws;
    float* xr      = (float*)(Wb + 0);                  // 32MB  in_proj..scan_y
    bf16*  h_h     = (bf16*) (Wb + 32 * MB);            // 4MB   rms..in_proj
    bf16*  h_l     = (bf16*) (Wb + 36 * MB);            // 4MB
    bf16*  u_h     = (bf16*) (Wb + 32 * MB);            // 8MB   conv..x_proj (over h)
    bf16*  u_l     = (bf16*) (Wb + 40 * MB);            // 8MB
    float* Pbuf    = (float*)(Wb + 32 * MB);            // 8MB   scan_part..comb (over u_h)
    float* Sbuf    = (float*)(Wb + 40 * MB);            // 8MB   scan_part..scan_y (over u_l)
    bf16*  y_h     = (bf16*) (Wb + 32 * MB);            // 8MB   scan_y..out_proj (over dead P)
    bf16*  wo_h    = (bf16*) (Wb + 40 * MB);            // 4MB   split_wo (after scan_y, over Sbuf)
    bf16*  wo_l    = (bf16*) (Wb + 44 * MB);            // 4MB
    float* u_t     = (float*)(Wb + 48 * MB);            // 16MB  conv..scan_y
    float* out_prt = (float*)(Wb + 48 * MB);            // 33.5MB out_proj..out_reduce (over u_t+delta_t+tail)
    bf16*  wi_h    = (bf16*) (Wb + 64 * MB);            // 8MB   split_all..in_proj
    bf16*  wi_l    = (bf16*) (Wb + 72 * MB);            // 8MB
    float* xp_prt  = (float*)(Wb + 64 * MB);            // 12.6MB x_proj..xdbl_reduce (over wi)
    float* delta_t = (float*)(Wb + 64 * MB);            // 16MB  dt_proj..scan_y (over xp_prt)
    bf16*  xp_h    = (bf16*) (Wb + 80 * MB);            // 512KB split_all..x_proj
    bf16*  xp_l    = (bf16*) (Wb + 80 * MB + 512 * KB); // 512KB
    bf16*  xdbl_h  = (bf16*) (Wb + 81 * MB);            // 384KB xdbl_reduce..dt_proj
    bf16*  xdbl_l  = (bf16*) (Wb + 81 * MB + 384 * KB); // 384KB
    float* bc_t    = (float*)(Wb + 81 * MB + 768 * KB); // 256KB xdbl_reduce..scan_y
    bf16*  dtw_h   = (bf16*) (Wb + 82 * MB);            // 256KB split_all..dt_proj
    bf16*  dtw_l   = (bf16*) (Wb + 82 * MB + 256 * KB); // 256KB

    // 1) RMSNorm -> h hi/lo
    k_rmsnorm<<<TOK, 256, 0, stream>>>(x, norm_w, h_h, h_l);
    // 2) fused weight splits (in_proj + dt_w + x_proj pad)
    k_split_all<<<(N4_WI + N4_DTW + N4_XP + 255) / 256, 256, 0, stream>>>(
        in_proj, dt_w, x_proj, wi_h, wi_l, dtw_h, dtw_l, xp_h, xp_l);
    // 3) in_proj: [2048,1024] x [4096,1024]^T -> xr  (bf16x3)
    k_gemm_bf16<2, 0><<<dim3(32, 16, 1), 256, 0, stream>>>(
        h_h, h_l, DM, wi_h, wi_l, DM, xr, 2 * DI, nullptr, TOK, 2 * DI, DM);
    // 4) sliding-window conv + SiLU -> u_h/u_l bf16 [tok][d] + u_t f32 [d][tok]
    k_conv_silu<<<512, 256, 0, stream>>>(xr, conv_w, conv_b, u_h, u_l, u_t);
    // 5) x_proj: split-K=16 partials (no atomics), bf16x3
    k_gemm_bf16<2, 5><<<dim3(1, 16, ZX), 256, 0, stream>>>(
        u_h, u_l, DI, xp_h, xp_l, DI, xp_prt, 96, nullptr, TOK, 96, DI / ZX);
    // 6) reduce partials + hi/lo split + B/C transpose
    k_xdbl_reduce<<<TOK / 2, 192, 0, stream>>>(xp_prt, xdbl_h, xdbl_l, bc_t);
    // 7) dt_proj + softplus -> delta_t [DI][TOK] (transposed epilogue; over dead xp_prt)
    k_gemm_bf16<2, 4><<<dim3(16, 16, 1), 256, 0, stream>>>(
        xdbl_h, xdbl_l, 96, dtw_h, dtw_l, DTR, delta_t, TOK, dt_b, TOK, DI, DTR);
    // 8) chunked scan (NC=32)
    k_scan_part<<<B_ * NC * (DI / 64), 256, 0, stream>>>(
        delta_t, u_t, bc_t, A_log, Pbuf, Sbuf);
    k_scan_comb<<<256, 256, 0, stream>>>(Pbuf, Sbuf);
    k_scan_y<<<B_ * NC * (DI / 64), 256, 0, stream>>>(
        delta_t, u_t, bc_t, xr, A_log, Dp, Sbuf, y_h);
    // 9) split out_proj weights (over dead Sbuf)
    k_split<<<2048, 256, 0, stream>>>(out_w, wo_h, wo_l, (DM * DI) / 4);
    // 10) out_proj: split-K=4 partials (no atomics), bf16x2
    k_gemm_bf16<1, 5><<<dim3(8, 16, ZO), 256, 0, stream>>>(
        y_h, nullptr, DI, wo_h, wo_l, DI, out_prt, DM, nullptr, TOK, DM, DI / ZO);
    // 11) reduce + residual -> out
    k_out_reduce<<<TOK * DM / 4 / 256, 256, 0, stream>>>(out_prt, x, out);
}